// Round 16
// baseline (16509.975 us; speedup 1.0000x reference)
//
#include <hip/hip_runtime.h>
#include <hip/hip_bf16.h>

#define T_LEN 8192
#define HD 256
#define D_EMB 300
#define NTAG 19
#define START_TAG 17
#define STOP_TAG 18

typedef unsigned long long u64;

// ---- agent scope (IC) atomics ----
__device__ __forceinline__ u64 a_load(const u64* p) {
  return __hip_atomic_load(p, __ATOMIC_RELAXED, __HIP_MEMORY_SCOPE_AGENT);
}
__device__ __forceinline__ void a_store(u64* p, u64 v) {
  __hip_atomic_store(p, v, __ATOMIC_RELAXED, __HIP_MEMORY_SCOPE_AGENT);
}
__device__ __forceinline__ int agent_add1(int* p) {
  return __hip_atomic_fetch_add(p, 1, __ATOMIC_RELAXED, __HIP_MEMORY_SCOPE_AGENT);
}
__device__ __forceinline__ bool agent_cas(int* p, int expv, int newv) {
  return __hip_atomic_compare_exchange_strong(p, &expv, newv, __ATOMIC_RELAXED,
                                              __ATOMIC_RELAXED, __HIP_MEMORY_SCOPE_AGENT);
}
__device__ __forceinline__ int agent_ldi(const int* p) {
  return __hip_atomic_load(p, __ATOMIC_RELAXED, __HIP_MEMORY_SCOPE_AGENT);
}

// ---- consumer fast probe (r9 best-measured): drop L1 (buffer_inv sc0), then
// sc0 load => fresh read of the XCD's shared L2. Producer publishes via atomic
// swap (RMWs execute at L2), so the value is guaranteed L2-resident.
__device__ __forceinline__ u64 fast_load(const u64* p) {
  u64 v;
  asm volatile("buffer_inv sc0\n\t"
               "global_load_dwordx2 %0, %1, off sc0\n\t"
               "s_waitcnt vmcnt(0)"
               : "=v"(v) : "v"(p) : "memory");
  return v;
}
__device__ __forceinline__ void l2_publish(u64* p, u64 v) {
  (void)__hip_atomic_exchange(p, v, __ATOMIC_RELAXED, __HIP_MEMORY_SCOPE_WORKGROUP);
}
__device__ __forceinline__ float rcp_(float x) { return __builtin_amdgcn_rcpf(x); }

// AGPR stash (r15-proven: VGPR_Count 56->88, weights stay on-register)
#define STASH(dst, src) \
  asm volatile("v_accvgpr_write_b32 %0, %1" : "=a"(dst) : "v"(src))

#define GETREG_XCC_ID (20 | (3 << 11))          // id=20, offset 0, width 4
#define HIDX(i) (((i) >> 4) * 20 + ((i) & 15))  // stride-20 LDS swizzle

// ds_swizzle xor-reduce (BitMode imm: (xor<<10)|0x1F) within 16-lane q-groups
#define SWZ(x, imm) __int_as_float(__builtin_amdgcn_ds_swizzle(__float_as_int(x), imm))

// padded fast-word addressing: each u64 on its own 128 B line (r9 layout)
#define FWORD(base, slot, i) ((base) + (((slot) * 256 + (i)) << 4))

// ---------------- kernel 1: xg[dir][t][1024] = emb[sent] @ w_ih.T + b --------
__global__ __launch_bounds__(512) void k_xg(
    const int* __restrict__ sent, const float* __restrict__ emb,
    const float* __restrict__ w_ih_f, const float* __restrict__ b_f,
    const float* __restrict__ w_ih_b, const float* __restrict__ b_b,
    float* __restrict__ xg)
{
  const int dir = blockIdx.y;
  const int t0 = blockIdx.x * 64;
  const float* wih  = dir ? w_ih_b : w_ih_f;
  const float* bias = dir ? b_b    : b_f;
  __shared__ float xlds[64][304];   // 77.8 KB
  __shared__ int sid[64];
  const int tid = threadIdx.x;
  if (tid < 64) {
    int t = t0 + tid;
    int ts = dir ? (T_LEN - 1 - t) : t;   // backward consumes reversed input
    sid[tid] = sent[ts];
  }
  __syncthreads();
  for (int idx = tid; idx < 64 * D_EMB; idx += 512) {
    int r = idx / D_EMB, k = idx - r * D_EMB;
    xlds[r][k] = emb[(size_t)sid[r] * D_EMB + k];
  }
  __syncthreads();
  float* xgo = xg + (size_t)dir * T_LEN * 1024;
#pragma unroll 1
  for (int rr = 0; rr < 2; ++rr) {
    int row = tid + rr * 512;            // 0..1023
    const float* wrow = wih + (size_t)row * D_EMB;
    float bb = bias[row];
    float acc[64];
#pragma unroll
    for (int i = 0; i < 64; ++i) acc[i] = bb;
#pragma unroll 1
    for (int k4 = 0; k4 < 75; ++k4) {    // 300 = 75*4
      float4 w4 = *(const float4*)(wrow + k4 * 4);
#pragma unroll
      for (int i = 0; i < 64; ++i) {
        float4 x4 = *(const float4*)&xlds[i][k4 * 4];
        acc[i] = fmaf(w4.x, x4.x, acc[i]);
        acc[i] = fmaf(w4.y, x4.y, acc[i]);
        acc[i] = fmaf(w4.z, x4.z, acc[i]);
        acc[i] = fmaf(w4.w, x4.w, acc[i]);
      }
    }
#pragma unroll
    for (int i = 0; i < 64; ++i)
      xgo[(size_t)(t0 + i) * 1024 + row] = acc[i];
  }
}

// ---------------- kernel 2: BiLSTM recurrence, same-XCD L2 fast path ---------
// 96 blocks of 512; election picks two 8-block cohorts on ONE XCD.
// Thread (jl 0..31, q 0..15) owns gate-rows {g*256+b*32+jl} cols [16q,16q+16)
// = 64 weight floats in AGPRs. Poll waves (0-3) carry NO other vmem: the xg
// stream is prefetched by wave-7 loader lanes (448..479, never poll) into a
// double-buffered LDS strip, so the poll's vmcnt(0) is exact (r15's hidden
// stall: poll drained its own wave's cold-HBM xg prefetch).
__global__ __launch_bounds__(512, 1) void k_lstm(
    const float* __restrict__ xg,
    const float* __restrict__ w_hh_f, const float* __restrict__ w_hh_b,
    const float* __restrict__ h0, const float* __restrict__ c0,
    float* __restrict__ h_out,          // [T][512]
    u64* __restrict__ hfast,            // [2 roles][2 slots][256] 128B-padded
    u64* __restrict__ hsafe,            // [2 roles][2 slots][256]
    int* __restrict__ elect)            // [0..15] cnt, [16] slot0, [17] slot1
{
  __shared__ int s_role, s_b;
  const int tid = threadIdx.x;
  if (tid == 0) {
    int xcd = __builtin_amdgcn_s_getreg(GETREG_XCC_ID) & 15;
    int tkt = agent_add1(&elect[xcd]);
    int role = -1, b = -1;
    if (tkt < 16) {
      int half = tkt >> 3;
      int cid = xcd * 2 + half + 1;     // nonzero cohort id
      b = tkt & 7;
      if ((tkt & 7) == 7) {             // 8th member claims a slot
        if (half == 0) {
          if (!agent_cas(&elect[16], 0, cid)) agent_cas(&elect[17], 0, cid);
        } else {
          if (!agent_cas(&elect[17], 0, cid)) agent_cas(&elect[16], 0, cid);
        }
      }
      int s0, s1;
      for (;;) {
        s0 = agent_ldi(&elect[16]); s1 = agent_ldi(&elect[17]);
        if (s0 != 0 && s1 != 0) break;
        __builtin_amdgcn_s_sleep(2);
      }
      if (s0 == cid) role = 0;
      else if (s1 == cid) role = 1;
    }
    s_role = role; s_b = b;
  }
  __syncthreads();
  const int role = s_role, b = s_b;
  if (role < 0) return;

  const float* whh = role ? w_hh_b : w_hh_f;
  const float* xgd = xg + (size_t)role * T_LEN * 1024;
  u64* fb = hfast + role * 8192;        // padded: word i at fb + (slot*256+i)*16
  u64* sb = hsafe + role * 512;
  const int jl = tid >> 4, q = tid & 15;     // j-local 0..31, col-group 0..15
  const int j = b * 32 + jl;                 // global h index 0..255
  const bool isq0 = (q == 0);

  const bool ispoll = (tid < 224);
  int pwi = 0;
  { int cch = tid >> 5; pwi = (cch + (cch >= b)) * 32 + (tid & 31); }

  // xg loader lanes: wave 7, lanes 448..479 (never poll)
  const bool isldr = (tid >= 448 && tid < 480);
  const int ll = tid - 448;                  // 0..31

  // weights -> 64 AGPRs (16 per gate), constant-indexed after full unroll
  float wst[64];
#pragma unroll
  for (int g2 = 0; g2 < 4; ++g2) {
    const float* wr = whh + (size_t)(g2 * 256 + j) * 256 + q * 16;
#pragma unroll
    for (int k = 0; k < 16; ++k) { STASH(wst[g2 * 16 + k], wr[k]); }
  }

  __shared__ float hlds[2][320];
  __shared__ float xglds[2][128];   // [slot][g*32 + row]: gate inputs for step s

  float c = 0.f;
  if (isq0) {
    c = c0[role * 256 + j];
    float h0v = h0[role * 256 + j];
    hlds[0][HIDX(j)] = h0v;
    u64 word = ((u64)__float_as_uint(h0v) << 32) | 1ull;
    l2_publish(FWORD(fb, 0, j), word);
    a_store(sb + j, word);
  }
  if (isldr) {
    int jj = b * 32 + ll;
    xglds[0][ll]      = xgd[jj];
    xglds[0][32 + ll] = xgd[256 + jj];
    xglds[0][64 + ll] = xgd[512 + jj];
    xglds[0][96 + ll] = xgd[768 + jj];
  }

  for (int s = 0; s < T_LEN; ++s) {
    const int slot = s & 1;
    if (ispoll) {
      const unsigned tag = (unsigned)(s + 1);
      u64* fwp = FWORD(fb, slot, pwi);
      u64* swp = sb + slot * 256 + pwi;
      u64 wv;
      for (int it = 0;; ++it) {
        wv = fast_load(fwp);
        if ((unsigned)wv == tag) break;
        if ((it & 3) == 3) {                 // periodic safe (IC) check
          wv = a_load(swp);
          if ((unsigned)wv == tag) break;
        }
      }
      hlds[slot][HIDX(pwi)] = __uint_as_float((unsigned)(wv >> 32));
    }
    __syncthreads();   // orders: h(slot) + xglds[slot] visible to all

    // loader: issue next step's xg loads (hidden under dot+reduce), LDS-write
    float p0 = 0.f, p1 = 0.f, p2 = 0.f, p3 = 0.f;
    if (isldr && s + 1 < T_LEN) {
      const float* xr = xgd + (size_t)(s + 1) * 1024 + b * 32 + ll;
      p0 = xr[0]; p1 = xr[256]; p2 = xr[512]; p3 = xr[768];
    }

    // h fragment: cols [16q,16q+16) = swizzle row q, contiguous 16 floats
    const float* hv = hlds[slot] + q * 20;
    float4 h40 = *(const float4*)(hv);
    float4 h41 = *(const float4*)(hv + 4);
    float4 h42 = *(const float4*)(hv + 8);
    float4 h43 = *(const float4*)(hv + 12);
    float hf[16] = { h40.x, h40.y, h40.z, h40.w,  h41.x, h41.y, h41.z, h41.w,
                     h42.x, h42.y, h42.z, h42.w,  h43.x, h43.y, h43.z, h43.w };
    float a0 = 0.f, a1 = 0.f, a2 = 0.f, a3 = 0.f;
#pragma unroll
    for (int k = 0; k < 16; ++k) {
      a0 = fmaf(wst[k],      hf[k], a0);
      a1 = fmaf(wst[16 + k], hf[k], a1);
      a2 = fmaf(wst[32 + k], hf[k], a2);
      a3 = fmaf(wst[48 + k], hf[k], a3);
    }
    // 16-lane xor-reduce via ds_swizzle immediates (within each q-group)
    a0 += SWZ(a0, 0x041F); a1 += SWZ(a1, 0x041F); a2 += SWZ(a2, 0x041F); a3 += SWZ(a3, 0x041F);
    a0 += SWZ(a0, 0x081F); a1 += SWZ(a1, 0x081F); a2 += SWZ(a2, 0x081F); a3 += SWZ(a3, 0x081F);
    a0 += SWZ(a0, 0x101F); a1 += SWZ(a1, 0x101F); a2 += SWZ(a2, 0x101F); a3 += SWZ(a3, 0x101F);
    a0 += SWZ(a0, 0x201F); a1 += SWZ(a1, 0x201F); a2 += SWZ(a2, 0x201F); a3 += SWZ(a3, 0x201F);

    // loader: deposit next step's gate inputs (drains its own loads only)
    if (isldr && s + 1 < T_LEN) {
      float* xd = xglds[slot ^ 1];
      xd[ll] = p0; xd[32 + ll] = p1; xd[64 + ll] = p2; xd[96 + ll] = p3;
    }

    if (isq0) {
      const float* xs = xglds[slot];
      float pi = a0 + xs[jl], pf = a1 + xs[32 + jl];
      float pg = a2 + xs[64 + jl], po = a3 + xs[96 + jl];
      float i_ = rcp_(1.f + __expf(-pi));
      float f_ = rcp_(1.f + __expf(-pf));
      float o_ = rcp_(1.f + __expf(-po));
      float eg = __expf(2.f * fabsf(pg));
      float g_ = copysignf(1.f - 2.f * rcp_(1.f + eg), pg);
      c = f_ * c + i_ * g_;
      float ec = __expf(2.f * fabsf(c));
      float th = copysignf(1.f - 2.f * rcp_(1.f + ec), c);
      float h = o_ * th;
      u64 word = ((u64)__float_as_uint(h) << 32) | (u64)(unsigned)(s + 2);
      l2_publish(FWORD(fb, slot ^ 1, j), word);      // fast first (critical)
      a_store(sb + (slot ^ 1) * 256 + j, word);      // safe liveness copy
      hlds[slot ^ 1][HIDX(j)] = h;
      int tor = role ? (T_LEN - 1 - s) : s;
      h_out[(size_t)tor * 512 + role * 256 + j] = h;
    }
  }
}

// ---------------- kernel 3: feats[t][19] = [hf,hb] @ w_out.T + b_out ---------
__global__ __launch_bounds__(640) void k_feats(
    const float* __restrict__ h, const float* __restrict__ w_out,
    const float* __restrict__ b_out, float* __restrict__ feats)
{
  const int tid = threadIdx.x;
  if (tid >= 32 * NTAG) return;
  const int tloc = tid / NTAG, j = tid - tloc * NTAG;
  const int t = blockIdx.x * 32 + tloc;
  const float* hr = h + (size_t)t * 512;
  const float* wr = w_out + (size_t)j * 512;
  float a0 = 0.f, a1 = 0.f, a2 = 0.f, a3 = 0.f;
  for (int k = 0; k < 512; k += 4) {
    float4 hv = *(const float4*)(hr + k);
    float4 wv = *(const float4*)(wr + k);
    a0 = fmaf(hv.x, wv.x, a0);
    a1 = fmaf(hv.y, wv.y, a1);
    a2 = fmaf(hv.z, wv.z, a2);
    a3 = fmaf(hv.w, wv.w, a3);
  }
  feats[(size_t)t * NTAG + j] = ((a0 + a1) + (a2 + a3)) + b_out[j];
}

// ---------------- kernel 4: Viterbi forward, named-scalar registers ----------
#define M2(va, xa, vb, xb) { bool c_ = (va) >= (vb); \
  va = c_ ? (va) : (vb); xa = c_ ? (xa) : (xb); }

#define VIT_STEP(FEATV, TT) { \
  float v0 = __shfl(fv, 0) + tr0,  v1 = __shfl(fv, 1) + tr1; \
  float v2 = __shfl(fv, 2) + tr2,  v3 = __shfl(fv, 3) + tr3; \
  float v4 = __shfl(fv, 4) + tr4,  v5 = __shfl(fv, 5) + tr5; \
  float v6 = __shfl(fv, 6) + tr6,  v7 = __shfl(fv, 7) + tr7; \
  float v8 = __shfl(fv, 8) + tr8,  v9 = __shfl(fv, 9) + tr9; \
  float v10 = __shfl(fv, 10) + tr10, v11 = __shfl(fv, 11) + tr11; \
  float v12 = __shfl(fv, 12) + tr12, v13 = __shfl(fv, 13) + tr13; \
  float v14 = __shfl(fv, 14) + tr14, v15 = __shfl(fv, 15) + tr15; \
  float v16 = __shfl(fv, 16) + tr16, v17 = __shfl(fv, 17) + tr17; \
  float v18 = __shfl(fv, 18) + tr18; \
  int x0 = 0, x2 = 2, x4 = 4, x6 = 6, x8 = 8, x10 = 10, x12 = 12, x14 = 14, x16 = 16; \
  M2(v0, x0, v1, 1)    M2(v2, x2, v3, 3)    M2(v4, x4, v5, 5) \
  M2(v6, x6, v7, 7)    M2(v8, x8, v9, 9)    M2(v10, x10, v11, 11) \
  M2(v12, x12, v13, 13) M2(v14, x14, v15, 15) M2(v16, x16, v17, 17) \
  M2(v0, x0, v2, x2)   M2(v4, x4, v6, x6)   M2(v8, x8, v10, x10) \
  M2(v12, x12, v14, x14) M2(v16, x16, v18, 18) \
  M2(v0, x0, v4, x4)   M2(v8, x8, v12, x12) \
  M2(v0, x0, v8, x8)   M2(v0, x0, v16, x16) \
  if (lane < NTAG) bps[(size_t)(TT) * NTAG + lane] = (unsigned char)x0; \
  fv = v0 + (FEATV); }

__global__ __launch_bounds__(64) void k_viterbi(
    const float* __restrict__ feats, const float* __restrict__ trans,
    float* __restrict__ fvfinal, unsigned char* __restrict__ bps)
{
  const int lane = threadIdx.x;
  const int j = (lane < NTAG) ? lane : (NTAG - 1);
  const float* trr = trans + (size_t)j * NTAG;
  float tr0 = trr[0], tr1 = trr[1], tr2 = trr[2], tr3 = trr[3], tr4 = trr[4];
  float tr5 = trr[5], tr6 = trr[6], tr7 = trr[7], tr8 = trr[8], tr9 = trr[9];
  float tr10 = trr[10], tr11 = trr[11], tr12 = trr[12], tr13 = trr[13];
  float tr14 = trr[14], tr15 = trr[15], tr16 = trr[16], tr17 = trr[17];
  float tr18 = trr[18];
  float fv = (j == START_TAG) ? 0.f : -10000.f;

  float fa0 = feats[0 * NTAG + j],  fa1 = feats[1 * NTAG + j];
  float fa2 = feats[2 * NTAG + j],  fa3 = feats[3 * NTAG + j];
  float fa4 = feats[4 * NTAG + j],  fa5 = feats[5 * NTAG + j];
  float fa6 = feats[6 * NTAG + j],  fa7 = feats[7 * NTAG + j];
  float fb0 = feats[8 * NTAG + j],  fb1 = feats[9 * NTAG + j];
  float fb2 = feats[10 * NTAG + j], fb3 = feats[11 * NTAG + j];
  float fb4 = feats[12 * NTAG + j], fb5 = feats[13 * NTAG + j];
  float fb6 = feats[14 * NTAG + j], fb7 = feats[15 * NTAG + j];

  for (int tb = 0; tb < 1024; ++tb) {
    const int t0 = tb * 8;
    VIT_STEP(fa0, t0 + 0) VIT_STEP(fa1, t0 + 1)
    VIT_STEP(fa2, t0 + 2) VIT_STEP(fa3, t0 + 3)
    VIT_STEP(fa4, t0 + 4) VIT_STEP(fa5, t0 + 5)
    VIT_STEP(fa6, t0 + 6) VIT_STEP(fa7, t0 + 7)
    fa0 = fb0; fa1 = fb1; fa2 = fb2; fa3 = fb3;
    fa4 = fb4; fa5 = fb5; fa6 = fb6; fa7 = fb7;
    if (tb < 1022) {
      const float* fr = feats + (size_t)(tb + 2) * 8 * NTAG + j;
      fb0 = fr[0 * NTAG]; fb1 = fr[1 * NTAG]; fb2 = fr[2 * NTAG]; fb3 = fr[3 * NTAG];
      fb4 = fr[4 * NTAG]; fb5 = fr[5 * NTAG]; fb6 = fr[6 * NTAG]; fb7 = fr[7 * NTAG];
    }
  }
  if (lane < NTAG) fvfinal[lane] = fv;
}

// ---------------- kernel 5: exact parallel backtrack via chunk composition ---
__global__ __launch_bounds__(1024) void k_backtrack(
    const float* __restrict__ fvfinal, const float* __restrict__ trans,
    const unsigned char* __restrict__ bps, float* __restrict__ out)
{
  __shared__ unsigned char maps[64][20];
  __shared__ unsigned char xc[64];
  __shared__ float score_sh;
  const int tid = threadIdx.x;

  for (int jid = tid; jid < 64 * NTAG; jid += 1024) {
    int c = jid / NTAG, tau = jid - c * NTAG;
    int y = tau;
    for (int t = (c + 1) * 128 - 1; t >= c * 128; --t)
      y = bps[(size_t)t * NTAG + y];
    maps[c][tau] = (unsigned char)y;
  }
  __syncthreads();

  if (tid == 0) {
    float best = -3.0e38f; int bi = 0;
    for (int p = 0; p < NTAG; ++p) {
      float s = fvfinal[p] + trans[STOP_TAG * NTAG + p];
      if (s > best) { best = s; bi = p; }
    }
    score_sh = best;
    int e = bi;
    for (int c = 63; c >= 0; --c) { xc[c] = (unsigned char)e; e = maps[c][e]; }
  }
  __syncthreads();

  if (tid == 0) out[0] = score_sh;
  if (tid < 64) {
    int c = tid;
    int y = xc[c];
    out[1 + ((c + 1) * 128 - 1)] = (float)y;
    for (int t = (c + 1) * 128 - 1; t > c * 128; --t) {
      y = bps[(size_t)t * NTAG + y];
      out[1 + t - 1] = (float)y;
    }
  }
}

// -----------------------------------------------------------------------------
extern "C" void kernel_launch(void* const* d_in, const int* in_sizes, int n_in,
                              void* d_out, int out_size, void* d_ws, size_t ws_size,
                              hipStream_t stream) {
  const int*   sent    = (const int*)d_in[0];
  const float* emb     = (const float*)d_in[1];
  const float* w_ih_f  = (const float*)d_in[2];
  const float* w_hh_f  = (const float*)d_in[3];
  const float* b_f     = (const float*)d_in[4];
  const float* w_ih_b  = (const float*)d_in[5];
  const float* w_hh_b  = (const float*)d_in[6];
  const float* b_b     = (const float*)d_in[7];
  const float* w_out   = (const float*)d_in[8];
  const float* b_out   = (const float*)d_in[9];
  const float* trans   = (const float*)d_in[10];
  const float* h0      = (const float*)d_in[11];
  const float* c0      = (const float*)d_in[12];
  float* out = (float*)d_out;

  char* ws = (char*)d_ws;
  float* xg            = (float*)(ws + 0);           // 64 MiB
  float* h_out         = (float*)(ws + 67108864);    // 16 MiB
  float* feats         = (float*)(ws + 83886080);    // T*19 f32
  float* fvfin         = (float*)(ws + 84508672);    // 32 f32
  unsigned char* bps   = (unsigned char*)(ws + 84508800);  // T*19 u8
  u64* hfast           = (u64*)(ws + 84664448);      // 128 KiB (128B-padded words)
  u64* hsafe           = (u64*)(ws + 84795520);      // 8 KiB
  int* elect           = (int*)(ws + 84803712);      // 18 ints (pad 128)

  // zero fast words + safe words + election state each call/replay (contiguous)
  (void)hipMemsetAsync(hfast, 0, 131072 + 8192 + 128, stream);

  k_xg      <<<dim3(128, 2), 512, 0, stream>>>(sent, emb, w_ih_f, b_f, w_ih_b, b_b, xg);
  k_lstm    <<<96, 512, 0, stream>>>(xg, w_hh_f, w_hh_b, h0, c0, h_out, hfast, hsafe, elect);
  k_feats   <<<256, 640, 0, stream>>>(h_out, w_out, b_out, feats);
  k_viterbi <<<1, 64, 0, stream>>>(feats, trans, fvfin, bps);
  k_backtrack<<<1, 1024, 0, stream>>>(fvfin, trans, bps, out);
}

// Round 17
// 13203.624 us; speedup vs baseline: 1.2504x; 1.2504x over previous
//
#include <hip/hip_runtime.h>
#include <hip/hip_bf16.h>

#define T_LEN 8192
#define HD 256
#define D_EMB 300
#define NTAG 19
#define START_TAG 17
#define STOP_TAG 18

typedef unsigned long long u64;

// ---- agent scope (IC) atomics ----
__device__ __forceinline__ u64 a_load(const u64* p) {
  return __hip_atomic_load(p, __ATOMIC_RELAXED, __HIP_MEMORY_SCOPE_AGENT);
}
__device__ __forceinline__ void a_store(u64* p, u64 v) {
  __hip_atomic_store(p, v, __ATOMIC_RELAXED, __HIP_MEMORY_SCOPE_AGENT);
}
__device__ __forceinline__ int agent_add1(int* p) {
  return __hip_atomic_fetch_add(p, 1, __ATOMIC_RELAXED, __HIP_MEMORY_SCOPE_AGENT);
}
__device__ __forceinline__ bool agent_cas(int* p, int expv, int newv) {
  return __hip_atomic_compare_exchange_strong(p, &expv, newv, __ATOMIC_RELAXED,
                                              __ATOMIC_RELAXED, __HIP_MEMORY_SCOPE_AGENT);
}
__device__ __forceinline__ int agent_ldi(const int* p) {
  return __hip_atomic_load(p, __ATOMIC_RELAXED, __HIP_MEMORY_SCOPE_AGENT);
}

// ---- consumer fast probe (r9 best-measured): drop L1 (buffer_inv sc0), then
// sc0 load => fresh read of the XCD's shared L2. Producer publishes via atomic
// swap (RMWs execute at L2), so the value is guaranteed L2-resident.
__device__ __forceinline__ u64 fast_load(const u64* p) {
  u64 v;
  asm volatile("buffer_inv sc0\n\t"
               "global_load_dwordx2 %0, %1, off sc0\n\t"
               "s_waitcnt vmcnt(0)"
               : "=v"(v) : "v"(p) : "memory");
  return v;
}
__device__ __forceinline__ void l2_publish(u64* p, u64 v) {
  (void)__hip_atomic_exchange(p, v, __ATOMIC_RELAXED, __HIP_MEMORY_SCOPE_WORKGROUP);
}
__device__ __forceinline__ float rcp_(float x) { return __builtin_amdgcn_rcpf(x); }

// AGPR stash: asm def is non-rematerializable; AGPR pool (unused — no MFMA)
// has zero allocation pressure => weights stay on-register the whole loop
// (r15-proven: VGPR_Count 56->88, k_lstm 11.53 -> 10.74 ms).
#define STASH(dst, src) \
  asm volatile("v_accvgpr_write_b32 %0, %1" : "=a"(dst) : "v"(src))

#define GETREG_XCC_ID (20 | (3 << 11))          // id=20, offset 0, width 4
#define HIDX(i) (((i) >> 4) * 20 + ((i) & 15))  // stride-20 LDS swizzle

// ds_swizzle xor-reduce (BitMode imm: (xor<<10)|0x1F) within 16-lane q-groups
#define SWZ(x, imm) __int_as_float(__builtin_amdgcn_ds_swizzle(__float_as_int(x), imm))

// padded fast-word addressing: each u64 on its own 128 B line (r9 layout)
#define FWORD(base, slot, i) ((base) + (((slot) * 256 + (i)) << 4))

// ---------------- kernel 1: xg[dir][t][1024] = emb[sent] @ w_ih.T + b --------
__global__ __launch_bounds__(512) void k_xg(
    const int* __restrict__ sent, const float* __restrict__ emb,
    const float* __restrict__ w_ih_f, const float* __restrict__ b_f,
    const float* __restrict__ w_ih_b, const float* __restrict__ b_b,
    float* __restrict__ xg)
{
  const int dir = blockIdx.y;
  const int t0 = blockIdx.x * 64;
  const float* wih  = dir ? w_ih_b : w_ih_f;
  const float* bias = dir ? b_b    : b_f;
  __shared__ float xlds[64][304];   // 77.8 KB
  __shared__ int sid[64];
  const int tid = threadIdx.x;
  if (tid < 64) {
    int t = t0 + tid;
    int ts = dir ? (T_LEN - 1 - t) : t;   // backward consumes reversed input
    sid[tid] = sent[ts];
  }
  __syncthreads();
  for (int idx = tid; idx < 64 * D_EMB; idx += 512) {
    int r = idx / D_EMB, k = idx - r * D_EMB;
    xlds[r][k] = emb[(size_t)sid[r] * D_EMB + k];
  }
  __syncthreads();
  float* xgo = xg + (size_t)dir * T_LEN * 1024;
#pragma unroll 1
  for (int rr = 0; rr < 2; ++rr) {
    int row = tid + rr * 512;            // 0..1023
    const float* wrow = wih + (size_t)row * D_EMB;
    float bb = bias[row];
    float acc[64];
#pragma unroll
    for (int i = 0; i < 64; ++i) acc[i] = bb;
#pragma unroll 1
    for (int k4 = 0; k4 < 75; ++k4) {    // 300 = 75*4
      float4 w4 = *(const float4*)(wrow + k4 * 4);
#pragma unroll
      for (int i = 0; i < 64; ++i) {
        float4 x4 = *(const float4*)&xlds[i][k4 * 4];
        acc[i] = fmaf(w4.x, x4.x, acc[i]);
        acc[i] = fmaf(w4.y, x4.y, acc[i]);
        acc[i] = fmaf(w4.z, x4.z, acc[i]);
        acc[i] = fmaf(w4.w, x4.w, acc[i]);
      }
    }
#pragma unroll
    for (int i = 0; i < 64; ++i)
      xgo[(size_t)(t0 + i) * 1024 + row] = acc[i];
  }
}

// ---------------- kernel 2: BiLSTM recurrence, same-XCD L2 fast path ---------
// 96 blocks of 512; election picks two 8-block cohorts, each on ONE XCD.
// Thread (jl 0..31, q 0..15) owns gate-rows {g*256 + b*32+jl} cols [16q,16q+16)
// = 64 weight floats, stashed in 64 AGPRs (see STASH). Poll = r9 inv+sc0 probe
// on 128B-padded words; IC safety copy every 4th miss guarantees liveness.
__global__ __launch_bounds__(512, 1) void k_lstm(
    const float* __restrict__ xg,
    const float* __restrict__ w_hh_f, const float* __restrict__ w_hh_b,
    const float* __restrict__ h0, const float* __restrict__ c0,
    float* __restrict__ h_out,          // [T][512]
    u64* __restrict__ hfast,            // [2 roles][2 slots][256] 128B-padded
    u64* __restrict__ hsafe,            // [2 roles][2 slots][256]
    int* __restrict__ elect)            // [0..15] cnt, [16] slot0, [17] slot1
{
  __shared__ int s_role, s_b;
  const int tid = threadIdx.x;
  if (tid == 0) {
    int xcd = __builtin_amdgcn_s_getreg(GETREG_XCC_ID) & 15;
    int tkt = agent_add1(&elect[xcd]);
    int role = -1, b = -1;
    if (tkt < 16) {
      int half = tkt >> 3;
      int cid = xcd * 2 + half + 1;     // nonzero cohort id
      b = tkt & 7;
      if ((tkt & 7) == 7) {             // 8th member claims a slot
        if (half == 0) {
          if (!agent_cas(&elect[16], 0, cid)) agent_cas(&elect[17], 0, cid);
        } else {
          if (!agent_cas(&elect[17], 0, cid)) agent_cas(&elect[16], 0, cid);
        }
      }
      int s0, s1;
      for (;;) {
        s0 = agent_ldi(&elect[16]); s1 = agent_ldi(&elect[17]);
        if (s0 != 0 && s1 != 0) break;
        __builtin_amdgcn_s_sleep(2);
      }
      if (s0 == cid) role = 0;
      else if (s1 == cid) role = 1;
    }
    s_role = role; s_b = b;
  }
  __syncthreads();
  const int role = s_role, b = s_b;
  if (role < 0) return;

  const float* whh = role ? w_hh_b : w_hh_f;
  const float* xgd = xg + (size_t)role * T_LEN * 1024;
  u64* fb = hfast + role * 8192;        // padded: word i at fb + (slot*256+i)*16
  u64* sb = hsafe + role * 512;
  const int jl = tid >> 4, q = tid & 15;     // j-local 0..31, col-group 0..15
  const int j = b * 32 + jl;                 // global h index 0..255
  const bool isq0 = (q == 0);

  const bool ispoll = (tid < 224);
  int pwi = 0;
  { int cch = tid >> 5; pwi = (cch + (cch >= b)) * 32 + (tid & 31); }

  // weights -> 64 AGPRs (16 per gate), constant-indexed after full unroll
  float wst[64];
#pragma unroll
  for (int g2 = 0; g2 < 4; ++g2) {
    const float* wr = whh + (size_t)(g2 * 256 + j) * 256 + q * 16;
#pragma unroll
    for (int k = 0; k < 16; ++k) { STASH(wst[g2 * 16 + k], wr[k]); }
  }

  __shared__ float hlds[2][320];

  float c = 0.f;
  float x0 = 0.f, x1 = 0.f, x2 = 0.f, x3 = 0.f;
  if (isq0) {
    c = c0[role * 256 + j];
    float h0v = h0[role * 256 + j];
    hlds[0][HIDX(j)] = h0v;
    u64 word = ((u64)__float_as_uint(h0v) << 32) | 1ull;
    l2_publish(FWORD(fb, 0, j), word);
    a_store(sb + j, word);
    x0 = xgd[j]; x1 = xgd[256 + j]; x2 = xgd[512 + j]; x3 = xgd[768 + j];
  }

  for (int s = 0; s < T_LEN; ++s) {
    const int slot = s & 1;
    if (ispoll) {
      const unsigned tag = (unsigned)(s + 1);
      u64* fwp = FWORD(fb, slot, pwi);
      u64* swp = sb + slot * 256 + pwi;
      u64 wv;
      for (int it = 0;; ++it) {
        wv = fast_load(fwp);
        if ((unsigned)wv == tag) break;
        if ((it & 3) == 3) {                 // periodic safe (IC) check
          wv = a_load(swp);
          if ((unsigned)wv == tag) break;
        }
      }
      hlds[slot][HIDX(pwi)] = __uint_as_float((unsigned)(wv >> 32));
    }
    __syncthreads();

    float n0 = 0.f, n1 = 0.f, n2 = 0.f, n3 = 0.f;
    if (isq0 && s + 1 < T_LEN) {
      const float* xr = xgd + (size_t)(s + 1) * 1024;
      n0 = xr[j]; n1 = xr[256 + j]; n2 = xr[512 + j]; n3 = xr[768 + j];
    }

    // h fragment: cols [16q,16q+16) = swizzle row q, contiguous 16 floats
    const float* hv = hlds[slot] + q * 20;
    float4 h40 = *(const float4*)(hv);
    float4 h41 = *(const float4*)(hv + 4);
    float4 h42 = *(const float4*)(hv + 8);
    float4 h43 = *(const float4*)(hv + 12);
    float hf[16] = { h40.x, h40.y, h40.z, h40.w,  h41.x, h41.y, h41.z, h41.w,
                     h42.x, h42.y, h42.z, h42.w,  h43.x, h43.y, h43.z, h43.w };
    float a0 = 0.f, a1 = 0.f, a2 = 0.f, a3 = 0.f;
#pragma unroll
    for (int k = 0; k < 16; ++k) {
      a0 = fmaf(wst[k],      hf[k], a0);
      a1 = fmaf(wst[16 + k], hf[k], a1);
      a2 = fmaf(wst[32 + k], hf[k], a2);
      a3 = fmaf(wst[48 + k], hf[k], a3);
    }
    // 16-lane xor-reduce via ds_swizzle immediates (within each q-group)
    a0 += SWZ(a0, 0x041F); a1 += SWZ(a1, 0x041F); a2 += SWZ(a2, 0x041F); a3 += SWZ(a3, 0x041F);
    a0 += SWZ(a0, 0x081F); a1 += SWZ(a1, 0x081F); a2 += SWZ(a2, 0x081F); a3 += SWZ(a3, 0x081F);
    a0 += SWZ(a0, 0x101F); a1 += SWZ(a1, 0x101F); a2 += SWZ(a2, 0x101F); a3 += SWZ(a3, 0x101F);
    a0 += SWZ(a0, 0x201F); a1 += SWZ(a1, 0x201F); a2 += SWZ(a2, 0x201F); a3 += SWZ(a3, 0x201F);

    if (isq0) {
      float pi = a0 + x0, pf = a1 + x1, pg = a2 + x2, po = a3 + x3;
      float i_ = rcp_(1.f + __expf(-pi));
      float f_ = rcp_(1.f + __expf(-pf));
      float o_ = rcp_(1.f + __expf(-po));
      float eg = __expf(2.f * fabsf(pg));
      float g_ = copysignf(1.f - 2.f * rcp_(1.f + eg), pg);
      c = f_ * c + i_ * g_;
      float ec = __expf(2.f * fabsf(c));
      float th = copysignf(1.f - 2.f * rcp_(1.f + ec), c);
      float h = o_ * th;
      u64 word = ((u64)__float_as_uint(h) << 32) | (u64)(unsigned)(s + 2);
      l2_publish(FWORD(fb, slot ^ 1, j), word);      // fast first (critical)
      a_store(sb + (slot ^ 1) * 256 + j, word);      // safe liveness copy
      hlds[slot ^ 1][HIDX(j)] = h;
      int tor = role ? (T_LEN - 1 - s) : s;
      h_out[(size_t)tor * 512 + role * 256 + j] = h;
    }
    x0 = n0; x1 = n1; x2 = n2; x3 = n3;
  }
}

// ---------------- kernel 3: feats[t][19] = [hf,hb] @ w_out.T + b_out ---------
__global__ __launch_bounds__(640) void k_feats(
    const float* __restrict__ h, const float* __restrict__ w_out,
    const float* __restrict__ b_out, float* __restrict__ feats)
{
  const int tid = threadIdx.x;
  if (tid >= 32 * NTAG) return;
  const int tloc = tid / NTAG, j = tid - tloc * NTAG;
  const int t = blockIdx.x * 32 + tloc;
  const float* hr = h + (size_t)t * 512;
  const float* wr = w_out + (size_t)j * 512;
  float a0 = 0.f, a1 = 0.f, a2 = 0.f, a3 = 0.f;
  for (int k = 0; k < 512; k += 4) {
    float4 hv = *(const float4*)(hr + k);
    float4 wv = *(const float4*)(wr + k);
    a0 = fmaf(hv.x, wv.x, a0);
    a1 = fmaf(hv.y, wv.y, a1);
    a2 = fmaf(hv.z, wv.z, a2);
    a3 = fmaf(hv.w, wv.w, a3);
  }
  feats[(size_t)t * NTAG + j] = ((a0 + a1) + (a2 + a3)) + b_out[j];
}

// ---------------- kernel 4: Viterbi forward, named-scalar registers ----------
#define M2(va, xa, vb, xb) { bool c_ = (va) >= (vb); \
  va = c_ ? (va) : (vb); xa = c_ ? (xa) : (xb); }

#define VIT_STEP(FEATV, TT) { \
  float v0 = __shfl(fv, 0) + tr0,  v1 = __shfl(fv, 1) + tr1; \
  float v2 = __shfl(fv, 2) + tr2,  v3 = __shfl(fv, 3) + tr3; \
  float v4 = __shfl(fv, 4) + tr4,  v5 = __shfl(fv, 5) + tr5; \
  float v6 = __shfl(fv, 6) + tr6,  v7 = __shfl(fv, 7) + tr7; \
  float v8 = __shfl(fv, 8) + tr8,  v9 = __shfl(fv, 9) + tr9; \
  float v10 = __shfl(fv, 10) + tr10, v11 = __shfl(fv, 11) + tr11; \
  float v12 = __shfl(fv, 12) + tr12, v13 = __shfl(fv, 13) + tr13; \
  float v14 = __shfl(fv, 14) + tr14, v15 = __shfl(fv, 15) + tr15; \
  float v16 = __shfl(fv, 16) + tr16, v17 = __shfl(fv, 17) + tr17; \
  float v18 = __shfl(fv, 18) + tr18; \
  int x0 = 0, x2 = 2, x4 = 4, x6 = 6, x8 = 8, x10 = 10, x12 = 12, x14 = 14, x16 = 16; \
  M2(v0, x0, v1, 1)    M2(v2, x2, v3, 3)    M2(v4, x4, v5, 5) \
  M2(v6, x6, v7, 7)    M2(v8, x8, v9, 9)    M2(v10, x10, v11, 11) \
  M2(v12, x12, v13, 13) M2(v14, x14, v15, 15) M2(v16, x16, v17, 17) \
  M2(v0, x0, v2, x2)   M2(v4, x4, v6, x6)   M2(v8, x8, v10, x10) \
  M2(v12, x12, v14, x14) M2(v16, x16, v18, 18) \
  M2(v0, x0, v4, x4)   M2(v8, x8, v12, x12) \
  M2(v0, x0, v8, x8)   M2(v0, x0, v16, x16) \
  if (lane < NTAG) bps[(size_t)(TT) * NTAG + lane] = (unsigned char)x0; \
  fv = v0 + (FEATV); }

__global__ __launch_bounds__(64) void k_viterbi(
    const float* __restrict__ feats, const float* __restrict__ trans,
    float* __restrict__ fvfinal, unsigned char* __restrict__ bps)
{
  const int lane = threadIdx.x;
  const int j = (lane < NTAG) ? lane : (NTAG - 1);
  const float* trr = trans + (size_t)j * NTAG;
  float tr0 = trr[0], tr1 = trr[1], tr2 = trr[2], tr3 = trr[3], tr4 = trr[4];
  float tr5 = trr[5], tr6 = trr[6], tr7 = trr[7], tr8 = trr[8], tr9 = trr[9];
  float tr10 = trr[10], tr11 = trr[11], tr12 = trr[12], tr13 = trr[13];
  float tr14 = trr[14], tr15 = trr[15], tr16 = trr[16], tr17 = trr[17];
  float tr18 = trr[18];
  float fv = (j == START_TAG) ? 0.f : -10000.f;

  float fa0 = feats[0 * NTAG + j],  fa1 = feats[1 * NTAG + j];
  float fa2 = feats[2 * NTAG + j],  fa3 = feats[3 * NTAG + j];
  float fa4 = feats[4 * NTAG + j],  fa5 = feats[5 * NTAG + j];
  float fa6 = feats[6 * NTAG + j],  fa7 = feats[7 * NTAG + j];
  float fb0 = feats[8 * NTAG + j],  fb1 = feats[9 * NTAG + j];
  float fb2 = feats[10 * NTAG + j], fb3 = feats[11 * NTAG + j];
  float fb4 = feats[12 * NTAG + j], fb5 = feats[13 * NTAG + j];
  float fb6 = feats[14 * NTAG + j], fb7 = feats[15 * NTAG + j];

  for (int tb = 0; tb < 1024; ++tb) {
    const int t0 = tb * 8;
    VIT_STEP(fa0, t0 + 0) VIT_STEP(fa1, t0 + 1)
    VIT_STEP(fa2, t0 + 2) VIT_STEP(fa3, t0 + 3)
    VIT_STEP(fa4, t0 + 4) VIT_STEP(fa5, t0 + 5)
    VIT_STEP(fa6, t0 + 6) VIT_STEP(fa7, t0 + 7)
    fa0 = fb0; fa1 = fb1; fa2 = fb2; fa3 = fb3;
    fa4 = fb4; fa5 = fb5; fa6 = fb6; fa7 = fb7;
    if (tb < 1022) {
      const float* fr = feats + (size_t)(tb + 2) * 8 * NTAG + j;
      fb0 = fr[0 * NTAG]; fb1 = fr[1 * NTAG]; fb2 = fr[2 * NTAG]; fb3 = fr[3 * NTAG];
      fb4 = fr[4 * NTAG]; fb5 = fr[5 * NTAG]; fb6 = fr[6 * NTAG]; fb7 = fr[7 * NTAG];
    }
  }
  if (lane < NTAG) fvfinal[lane] = fv;
}

// ---------------- kernel 5: exact parallel backtrack via chunk composition ---
__global__ __launch_bounds__(1024) void k_backtrack(
    const float* __restrict__ fvfinal, const float* __restrict__ trans,
    const unsigned char* __restrict__ bps, float* __restrict__ out)
{
  __shared__ unsigned char maps[64][20];
  __shared__ unsigned char xc[64];
  __shared__ float score_sh;
  const int tid = threadIdx.x;

  for (int jid = tid; jid < 64 * NTAG; jid += 1024) {
    int c = jid / NTAG, tau = jid - c * NTAG;
    int y = tau;
    for (int t = (c + 1) * 128 - 1; t >= c * 128; --t)
      y = bps[(size_t)t * NTAG + y];
    maps[c][tau] = (unsigned char)y;
  }
  __syncthreads();

  if (tid == 0) {
    float best = -3.0e38f; int bi = 0;
    for (int p = 0; p < NTAG; ++p) {
      float s = fvfinal[p] + trans[STOP_TAG * NTAG + p];
      if (s > best) { best = s; bi = p; }
    }
    score_sh = best;
    int e = bi;
    for (int c = 63; c >= 0; --c) { xc[c] = (unsigned char)e; e = maps[c][e]; }
  }
  __syncthreads();

  if (tid == 0) out[0] = score_sh;
  if (tid < 64) {
    int c = tid;
    int y = xc[c];
    out[1 + ((c + 1) * 128 - 1)] = (float)y;
    for (int t = (c + 1) * 128 - 1; t > c * 128; --t) {
      y = bps[(size_t)t * NTAG + y];
      out[1 + t - 1] = (float)y;
    }
  }
}

// -----------------------------------------------------------------------------
extern "C" void kernel_launch(void* const* d_in, const int* in_sizes, int n_in,
                              void* d_out, int out_size, void* d_ws, size_t ws_size,
                              hipStream_t stream) {
  const int*   sent    = (const int*)d_in[0];
  const float* emb     = (const float*)d_in[1];
  const float* w_ih_f  = (const float*)d_in[2];
  const float* w_hh_f  = (const float*)d_in[3];
  const float* b_f     = (const float*)d_in[4];
  const float* w_ih_b  = (const float*)d_in[5];
  const float* w_hh_b  = (const float*)d_in[6];
  const float* b_b     = (const float*)d_in[7];
  const float* w_out   = (const float*)d_in[8];
  const float* b_out   = (const float*)d_in[9];
  const float* trans   = (const float*)d_in[10];
  const float* h0      = (const float*)d_in[11];
  const float* c0      = (const float*)d_in[12];
  float* out = (float*)d_out;

  char* ws = (char*)d_ws;
  float* xg            = (float*)(ws + 0);           // 64 MiB
  float* h_out         = (float*)(ws + 67108864);    // 16 MiB
  float* feats         = (float*)(ws + 83886080);    // T*19 f32
  float* fvfin         = (float*)(ws + 84508672);    // 32 f32
  unsigned char* bps   = (unsigned char*)(ws + 84508800);  // T*19 u8
  u64* hfast           = (u64*)(ws + 84664448);      // 128 KiB (128B-padded words)
  u64* hsafe           = (u64*)(ws + 84795520);      // 8 KiB
  int* elect           = (int*)(ws + 84803712);      // 18 ints (pad 128)

  // zero fast words + safe words + election state each call/replay (contiguous)
  (void)hipMemsetAsync(hfast, 0, 131072 + 8192 + 128, stream);

  k_xg      <<<dim3(128, 2), 512, 0, stream>>>(sent, emb, w_ih_f, b_f, w_ih_b, b_b, xg);
  k_lstm    <<<96, 512, 0, stream>>>(xg, w_hh_f, w_hh_b, h0, c0, h_out, hfast, hsafe, elect);
  k_feats   <<<256, 640, 0, stream>>>(h_out, w_out, b_out, feats);
  k_viterbi <<<1, 64, 0, stream>>>(feats, trans, fvfin, bps);
  k_backtrack<<<1, 1024, 0, stream>>>(fvfin, trans, bps, out);
}